// Round 6
// baseline (185.103 us; speedup 1.0000x reference)
//
#include <hip/hip_runtime.h>
#include <stdint.h>

#define BI 128
#define BT 128
#define KIMG 36
#define LCAP 64
#define DD 1024
#define MP 48        // imgs K padded to 3x16 for MFMA alignment
#define MB 96        // rows per block = 2 padded images
#define NB 256       // cols per block = 4 captions
#define ABUF 6144    // one A staging buffer: 96 rows x 64 B

typedef _Float16 h4 __attribute__((ext_vector_type(4)));
typedef _Float16 h8 __attribute__((ext_vector_type(8)));
typedef float f4 __attribute__((ext_vector_type(4)));

__device__ __forceinline__ float wave_red_sum(float v) {
#pragma unroll
  for (int o = 1; o < 64; o <<= 1) v += __shfl_xor(v, o, 64);
  return v;
}
__device__ __forceinline__ float wave_red_max(float v) {
#pragma unroll
  for (int o = 1; o < 64; o <<= 1) v = fmaxf(v, __shfl_xor(v, o, 64));
  return v;
}

// ---------------------------------------------------------------------------
// Kernel 1: add EPS, L2-normalize rows over D=1024, cast to fp16.
// imgs rows go to padded [BI][MP=48][DD] layout (rows 36..47 = 0).
// ---------------------------------------------------------------------------
__global__ __launch_bounds__(256) void norm_kernel(
    const float* __restrict__ imgs, const float* __restrict__ caps,
    _Float16* __restrict__ Ah, _Float16* __restrict__ Bh) {
  int row = blockIdx.x;
  int tid = threadIdx.x;
  const float* src;
  _Float16* dst;
  if (row < BI * MP) {
    int i = row / MP, k = row - i * MP;
    dst = Ah + (size_t)row * DD;
    if (k >= KIMG) {           // zero padding rows (block-uniform branch)
      h4 z = {};
      ((h4*)dst)[tid] = z;
      return;
    }
    src = imgs + ((size_t)i * KIMG + k) * DD;
  } else {
    int r = row - BI * MP;
    dst = Bh + (size_t)r * DD;
    src = caps + (size_t)r * DD;
  }
  float4 x = ((const float4*)src)[tid];
  x.x += 1e-6f; x.y += 1e-6f; x.z += 1e-6f; x.w += 1e-6f;
  float ss = x.x * x.x + x.y * x.y + x.z * x.z + x.w * x.w;
  ss = wave_red_sum(ss);
  __shared__ float red[4];
  int lane = tid & 63, w = tid >> 6;
  if (lane == 0) red[w] = ss;
  __syncthreads();
  float scale = rsqrtf(red[0] + red[1] + red[2] + red[3]);
  h4 o;
  o[0] = (_Float16)(x.x * scale);
  o[1] = (_Float16)(x.y * scale);
  o[2] = (_Float16)(x.z * scale);
  o[3] = (_Float16)(x.w * scale);
  ((h4*)dst)[tid] = o;
}

// ---------------------------------------------------------------------------
// Kernel 2: 2 images x 4 captions per block (96x256), wave w = caption w.
// A (shared by 4 waves): ring-3 swizzled LDS staging (18 KB total).
// B (private per wave): DIRECT global->VGPR coalesced dwordx4 loads, ping-pong
// prefetched one step ahead (no LDS transit at all).
// Per step: {issue BF(t+1), issue A-stage(t+2), ds_read af(t), 24 MFMA,
// s_waitcnt vmcnt(nch), s_barrier}. Counted vmcnt keeps A(t+2) in flight.
// Swizzle (A only): 16B-slot involution s ^= (s>>3)&7; LDS dest linear,
// global source pre-swizzled (rule 21), frag reads apply same involution.
// ---------------------------------------------------------------------------
__global__ __launch_bounds__(256, 2) void sims_kernel(
    const _Float16* __restrict__ Ah, const _Float16* __restrict__ Bh,
    const int* __restrict__ img_lens, const int* __restrict__ cap_lens,
    float* __restrict__ out) {
  __shared__ char stage[3 * ABUF] __attribute__((aligned(16)));

  int tid = threadIdx.x;
  int lane = tid & 63;
  int w = tid >> 6;       // wave = caption within quad
  int bx = blockIdx.x;    // caption quad 0..31
  int by = blockIdx.y;    // image pair 0..63
  int fr = lane & 15;
  int fq = lane >> 4;

  const size_t arow0 = (size_t)by * MB;
  const size_t brow0 = (size_t)bx * NB;

  // ---- A staging: 6 chunks of 1 KB; waves own {0-1},{2-3},{4},{5} ----
  const int c0 = (w < 2) ? 2 * w : w + 2;
  const int nch = (w < 2) ? 2 : 1;
  int s0 = c0 * 64 + lane;
  int sw0 = s0 ^ ((s0 >> 3) & 7);
  const _Float16* gpA = Ah + (arow0 + (sw0 >> 2)) * DD + (sw0 & 3) * 8;
  const int lds0 = c0 * 1024 + lane * 16;

  // ---- af LDS read base: swizzle XOR is mi-invariant (64mi ≡ 0 mod 8) ----
  int sl = 4 * fr + fq;
  const int aoff0 = (sl ^ ((sl >> 3) & 7)) * 16;

  // ---- B direct pointers: bf[ni] = rows (brow0+64w+16ni+fr), k = fq*8.. ----
  const _Float16* bp0 = Bh + (brow0 + 64 * w + fr) * DD + fq * 8;
  const _Float16* bp1 = bp0 + 16 * DD;
  const _Float16* bp2 = bp0 + 32 * DD;
  const _Float16* bp3 = bp0 + 48 * DD;

  f4 acc[6][4] = {};
  h8 bfA[4], bfB[4];

  auto STAGE = [&](int buf, int k0) {
    __builtin_amdgcn_global_load_lds(
        (const __attribute__((address_space(1))) void*)(gpA + k0),
        (__attribute__((address_space(3))) void*)(stage + buf * ABUF + lds0), 16, 0, 0);
    if (nch == 2)
      __builtin_amdgcn_global_load_lds(
          (const __attribute__((address_space(1))) void*)(gpA + 16 * DD + k0),
          (__attribute__((address_space(3))) void*)(stage + buf * ABUF + lds0 + 1024), 16, 0, 0);
  };
  auto LOADB = [&](h8(&bf)[4], int k0) {
    bf[0] = *(const h8*)(bp0 + k0);
    bf[1] = *(const h8*)(bp1 + k0);
    bf[2] = *(const h8*)(bp2 + k0);
    bf[3] = *(const h8*)(bp3 + k0);
  };
  auto COMPUTE = [&](int bufR, h8(&bf)[4]) {
    const char* rb = stage + bufR * ABUF;
    h8 af[6];
#pragma unroll
    for (int mi = 0; mi < 6; ++mi) af[mi] = *(const h8*)(rb + aoff0 + 1024 * mi);
    __builtin_amdgcn_s_setprio(1);
#pragma unroll
    for (int mi = 0; mi < 6; ++mi)
#pragma unroll
      for (int ni = 0; ni < 4; ++ni)
        acc[mi][ni] = __builtin_amdgcn_mfma_f32_16x16x32_f16(af[mi], bf[ni], acc[mi][ni], 0, 0, 0);
    __builtin_amdgcn_s_setprio(0);
  };
  auto WAITN = [&]() {
    if (w < 2) asm volatile("s_waitcnt vmcnt(2)" ::: "memory");
    else       asm volatile("s_waitcnt vmcnt(1)" ::: "memory");
  };
  // steady body: end-of-body wait establishes {A(t+1) visible, BF(t+1) in reg}
  auto BODY = [&](int t, int bufR, int bufW, h8(&cur)[4], h8(&nxt)[4]) {
    LOADB(nxt, 32 * (t + 1));               // BF(t+1) -> regs
    __builtin_amdgcn_sched_barrier(0);
    STAGE(bufW, 32 * (t + 2));              // A(t+2) -> ring slot
    __builtin_amdgcn_sched_barrier(0);
    COMPUTE(bufR, cur);                     // af(t) reads + 24 MFMA
    WAITN();                                // drain A(t+1)+BF(t+1); keep A(t+2)
    __builtin_amdgcn_s_barrier();
    __builtin_amdgcn_sched_barrier(0);
  };

  // ---- prologue: A(0), BF(0), A(1); drain A(0)+BF(0); keep A(1) ----
  STAGE(0, 0);
  LOADB(bfA, 0);
  STAGE(1, 32);
  WAITN();
  __builtin_amdgcn_s_barrier();
  __builtin_amdgcn_sched_barrier(0);

  // ---- main loop: 30 steady bodies (unroll 6 = lcm(ring3, pingpong2)) ----
  for (int tb = 0; tb < 30; tb += 6) {
    BODY(tb + 0, 0, 2, bfA, bfB);
    BODY(tb + 1, 1, 0, bfB, bfA);
    BODY(tb + 2, 2, 1, bfA, bfB);
    BODY(tb + 3, 0, 2, bfB, bfA);
    BODY(tb + 4, 1, 0, bfA, bfB);
    BODY(tb + 5, 2, 1, bfB, bfA);
  }
  // t = 30: BF(31) only; drain everything
  LOADB(bfB, 32 * 31);
  __builtin_amdgcn_sched_barrier(0);
  COMPUTE(0, bfA);
  asm volatile("s_waitcnt vmcnt(0)" ::: "memory");
  __builtin_amdgcn_s_barrier();
  __builtin_amdgcn_sched_barrier(0);
  // t = 31
  COMPUTE(1, bfB);

  // ---- register epilogue: C/D layout col=16*ni+fr, row=16*mi+4*fq+j ----
  int t = bx * 4 + w;
  int Lt = cap_lens[t];

#pragma unroll
  for (int img = 0; img < 2; ++img) {
    int Ki = img_lens[2 * by + img];

    float m = -1e30f;
#pragma unroll
    for (int mi = 0; mi < 3; ++mi)
#pragma unroll
      for (int ni = 0; ni < 4; ++ni)
#pragma unroll
        for (int j = 0; j < 4; ++j) {
          bool valid = (16 * mi + 4 * fq + j < Ki) && (16 * ni + fr < Lt);
          if (valid) m = fmaxf(m, acc[3 * img + mi][ni][j]);
        }
    m = wave_red_max(m);

    float rowe[3][4] = {}, rowes[3][4] = {}, cole[4] = {}, coles[4] = {};
#pragma unroll
    for (int mi = 0; mi < 3; ++mi)
#pragma unroll
      for (int ni = 0; ni < 4; ++ni)
#pragma unroll
        for (int j = 0; j < 4; ++j) {
          float s = acc[3 * img + mi][ni][j];
          bool valid = (16 * mi + 4 * fq + j < Ki) && (16 * ni + fr < Lt);
          float e = valid ? __expf((s - m) * 20.0f) : 0.f;  // 1/LAMB = 20
          float es = e * s;
          rowe[mi][j] += e;
          rowes[mi][j] += es;
          cole[ni] += e;
          coles[ni] += es;
        }

    // v2t: per row, reduce over cols (fr lanes), then accumulate rows
    float part = 0.f;
#pragma unroll
    for (int mi = 0; mi < 3; ++mi)
#pragma unroll
      for (int j = 0; j < 4; ++j) {
        float Re = rowe[mi][j], Res = rowes[mi][j];
#pragma unroll
        for (int o = 1; o < 16; o <<= 1) {
          Re += __shfl_xor(Re, o, 64);
          Res += __shfl_xor(Res, o, 64);
        }
        int row = 16 * mi + 4 * fq + j;
        if (fr == 0 && row < Ki) part += (Res / Re) * (0.5f / (float)Ki);
      }
    // t2v: per col, reduce over rows (fq lanes), then accumulate cols
#pragma unroll
    for (int ni = 0; ni < 4; ++ni) {
      float Ce = cole[ni], Ces = coles[ni];
#pragma unroll
      for (int o = 16; o < 64; o <<= 1) {
        Ce += __shfl_xor(Ce, o, 64);
        Ces += __shfl_xor(Ces, o, 64);
      }
      int l = 16 * ni + fr;
      if (fq == 0 && l < Lt) part += (Ces / Ce) * (0.5f / (float)Lt);
    }
    float sim = wave_red_sum(part);
    if (lane == 0) out[(size_t)(2 * by + img) * BT + t] = sim;
  }
}

extern "C" void kernel_launch(void* const* d_in, const int* in_sizes, int n_in,
                              void* d_out, int out_size, void* d_ws, size_t ws_size,
                              hipStream_t stream) {
  // setup_inputs order: img_cls, imgs, cap_cls, caps, img_lens, cap_lens
  const float* imgs = (const float*)d_in[1];
  const float* caps = (const float*)d_in[3];
  const int* img_lens = (const int*)d_in[4];
  const int* cap_lens = (const int*)d_in[5];
  float* out = (float*)d_out;

  _Float16* Ah = (_Float16*)d_ws;                    // [BI*MP][DD] = 12.6 MB
  _Float16* Bh = Ah + (size_t)BI * MP * DD;          // [BT*LCAP][DD] = 16.8 MB

  norm_kernel<<<BI * MP + BT * LCAP, 256, 0, stream>>>(imgs, caps, Ah, Bh);
  sims_kernel<<<dim3(BT / 4, BI / 2), 256, 0, stream>>>(Ah, Bh, img_lens, cap_lens, out);
}

// Round 7
// 150.790 us; speedup vs baseline: 1.2276x; 1.2276x over previous
//
#include <hip/hip_runtime.h>
#include <stdint.h>

#define BI 128
#define BT 128
#define KIMG 36
#define LCAP 64
#define DD 1024
#define MP 48        // imgs K padded to 3x16 for MFMA alignment
#define MB 96        // rows per block = 2 padded images
#define NB 256       // cols per block = 4 captions
#define ASLOTS 384   // A region 16B-slots (96 rows x 64 B)
#define ABYTES 6144
#define STG_BYTES 22528  // one staging buffer (A 6KB + B 16KB)

typedef _Float16 h4 __attribute__((ext_vector_type(4)));
typedef _Float16 h8 __attribute__((ext_vector_type(8)));
typedef float f4 __attribute__((ext_vector_type(4)));

__device__ __forceinline__ float wave_red_sum(float v) {
#pragma unroll
  for (int o = 1; o < 64; o <<= 1) v += __shfl_xor(v, o, 64);
  return v;
}
__device__ __forceinline__ float wave_red_max(float v) {
#pragma unroll
  for (int o = 1; o < 64; o <<= 1) v = fmaxf(v, __shfl_xor(v, o, 64));
  return v;
}

// ---------------------------------------------------------------------------
// Kernel 1: add EPS, L2-normalize rows over D=1024, cast to fp16.
// imgs rows go to padded [BI][MP=48][DD] layout (rows 36..47 = 0).
// ---------------------------------------------------------------------------
__global__ __launch_bounds__(256) void norm_kernel(
    const float* __restrict__ imgs, const float* __restrict__ caps,
    _Float16* __restrict__ Ah, _Float16* __restrict__ Bh) {
  int row = blockIdx.x;
  int tid = threadIdx.x;
  const float* src;
  _Float16* dst;
  if (row < BI * MP) {
    int i = row / MP, k = row - i * MP;
    dst = Ah + (size_t)row * DD;
    if (k >= KIMG) {           // zero padding rows (block-uniform branch)
      h4 z = {};
      ((h4*)dst)[tid] = z;
      return;
    }
    src = imgs + ((size_t)i * KIMG + k) * DD;
  } else {
    int r = row - BI * MP;
    dst = Bh + (size_t)r * DD;
    src = caps + (size_t)r * DD;
  }
  float4 x = ((const float4*)src)[tid];
  x.x += 1e-6f; x.y += 1e-6f; x.z += 1e-6f; x.w += 1e-6f;
  float ss = x.x * x.x + x.y * x.y + x.z * x.z + x.w * x.w;
  ss = wave_red_sum(ss);
  __shared__ float red[4];
  int lane = tid & 63, w = tid >> 6;
  if (lane == 0) red[w] = ss;
  __syncthreads();
  float scale = rsqrtf(red[0] + red[1] + red[2] + red[3]);
  h4 o;
  o[0] = (_Float16)(x.x * scale);
  o[1] = (_Float16)(x.y * scale);
  o[2] = (_Float16)(x.z * scale);
  o[3] = (_Float16)(x.w * scale);
  ((h4*)dst)[tid] = o;
}

// ---------------------------------------------------------------------------
// Kernel 2: 2 images x 4 captions per block (96x256 tile), wave w = caption w.
// R3 structure (champion): double-buffered swizzled LDS, 2-phase pipeline
// (STAGE next || compute cur, single barrier per k-step), 3 blocks/CU.
// NEW: XCD-aware bijective block swizzle — XCD x owns caption-quads
// bx in {4x..4x+3} (4 B-panels = 2 MB < 4 MB L2/XCD); consecutive slots
// share `by` so the A panel is L2-reused too.
// Swizzle: 16B-slot involution s ^= (s>>3)&7 per region; LDS dest linear,
// global source pre-swizzled (rule 21), frag reads apply same involution.
// ---------------------------------------------------------------------------
__global__ __launch_bounds__(256, 3) void sims_kernel(
    const _Float16* __restrict__ Ah, const _Float16* __restrict__ Bh,
    const int* __restrict__ img_lens, const int* __restrict__ cap_lens,
    float* __restrict__ out) {
  __shared__ char stage[2 * STG_BYTES] __attribute__((aligned(16)));

  int tid = threadIdx.x;
  int lane = tid & 63;
  int w = tid >> 6;       // wave = caption within quad

  // ---- XCD-aware bijective remap: grid is 1-D 2048 ----
  int wgid = blockIdx.x;
  int xcd = wgid & 7;          // HW round-robins consecutive ids over 8 XCDs
  int slot = wgid >> 3;        // 256 slots per XCD
  int bx = 4 * xcd + (slot & 3);   // caption quad 0..31 (4 per XCD)
  int by = slot >> 2;              // image pair 0..63 (shared by 4 slots)

  int fr = lane & 15;
  int fq = lane >> 4;

  const size_t arow0 = (size_t)by * MB;    // into padded A rows
  const size_t brow0 = (size_t)bx * NB;

  // ---- staging plan: wave w owns contiguous chunks; one base ptr + stride --
  // chunks: w0:0-5 (A), w1:6-11, w2:12-16, w3:17-21 (B). 64 slots/chunk.
  int c0 = 6 * w - ((w >> 1) & (w & 1));   // {0,6,12,17}
  int nch = (w < 2) ? 6 : 5;
  int s0 = c0 * 64 + lane;
  bool isA = (w == 0);
  int srel = isA ? s0 : s0 - ASLOTS;
  int sw0 = srel ^ ((srel >> 3) & 7);
  const _Float16* gp0 =
      (isA ? Ah + arow0 * DD : Bh + brow0 * DD) + (size_t)(sw0 >> 2) * DD + (sw0 & 3) * 8;
  const int lds0 = c0 * 1024 + lane * 16;

  // ---- swizzled fragment byte offsets (k-invariant) ----
  int aoff[6], boff[4];
#pragma unroll
  for (int mi = 0; mi < 6; ++mi) {
    int s = (16 * mi + fr) * 4 + fq;
    aoff[mi] = (s ^ ((s >> 3) & 7)) * 16;
  }
#pragma unroll
  for (int ni = 0; ni < 4; ++ni) {
    int s = (64 * w + 16 * ni + fr) * 4 + fq;
    boff[ni] = ABYTES + (s ^ ((s >> 3) & 7)) * 16;
  }

  auto STAGE = [&](int buf, int k0) {
#pragma unroll
    for (int it = 0; it < 6; ++it) {
      if (it < nch) {
        __builtin_amdgcn_global_load_lds(
            (const __attribute__((address_space(1))) void*)(gp0 + (size_t)it * 16 * DD + k0),
            (__attribute__((address_space(3))) void*)(stage + buf * STG_BYTES + lds0 + it * 1024),
            16, 0, 0);
      }
    }
  };

  f4 acc[6][4] = {};

  STAGE(0, 0);
  __syncthreads();

  for (int t = 0; t < 32; ++t) {
    const char* rb = stage + (t & 1) * STG_BYTES;
    if (t < 31) STAGE((t + 1) & 1, 32 * (t + 1));
    h8 af[6], bf[4];
#pragma unroll
    for (int mi = 0; mi < 6; ++mi)
      af[mi] = *(const h8*)(rb + aoff[mi]);
#pragma unroll
    for (int ni = 0; ni < 4; ++ni)
      bf[ni] = *(const h8*)(rb + boff[ni]);
#pragma unroll
    for (int mi = 0; mi < 6; ++mi)
#pragma unroll
      for (int ni = 0; ni < 4; ++ni)
        acc[mi][ni] = __builtin_amdgcn_mfma_f32_16x16x32_f16(
            af[mi], bf[ni], acc[mi][ni], 0, 0, 0);
    __syncthreads();
  }

  // ---- register epilogue: C/D layout col=16*ni+fr, row=16*mi+4*fq+j ----
  int t = bx * 4 + w;
  int Lt = cap_lens[t];

#pragma unroll
  for (int img = 0; img < 2; ++img) {
    int Ki = img_lens[2 * by + img];

    float m = -1e30f;
#pragma unroll
    for (int mi = 0; mi < 3; ++mi)
#pragma unroll
      for (int ni = 0; ni < 4; ++ni)
#pragma unroll
        for (int j = 0; j < 4; ++j) {
          bool valid = (16 * mi + 4 * fq + j < Ki) && (16 * ni + fr < Lt);
          if (valid) m = fmaxf(m, acc[3 * img + mi][ni][j]);
        }
    m = wave_red_max(m);

    float rowe[3][4] = {}, rowes[3][4] = {}, cole[4] = {}, coles[4] = {};
#pragma unroll
    for (int mi = 0; mi < 3; ++mi)
#pragma unroll
      for (int ni = 0; ni < 4; ++ni)
#pragma unroll
        for (int j = 0; j < 4; ++j) {
          float s = acc[3 * img + mi][ni][j];
          bool valid = (16 * mi + 4 * fq + j < Ki) && (16 * ni + fr < Lt);
          float e = valid ? __expf((s - m) * 20.0f) : 0.f;  // 1/LAMB = 20
          float es = e * s;
          rowe[mi][j] += e;
          rowes[mi][j] += es;
          cole[ni] += e;
          coles[ni] += es;
        }

    // v2t: per row, reduce over cols (fr lanes), then accumulate rows
    float part = 0.f;
#pragma unroll
    for (int mi = 0; mi < 3; ++mi)
#pragma unroll
      for (int j = 0; j < 4; ++j) {
        float Re = rowe[mi][j], Res = rowes[mi][j];
#pragma unroll
        for (int o = 1; o < 16; o <<= 1) {
          Re += __shfl_xor(Re, o, 64);
          Res += __shfl_xor(Res, o, 64);
        }
        int row = 16 * mi + 4 * fq + j;
        if (fr == 0 && row < Ki) part += (Res / Re) * (0.5f / (float)Ki);
      }
    // t2v: per col, reduce over rows (fq lanes), then accumulate cols
#pragma unroll
    for (int ni = 0; ni < 4; ++ni) {
      float Ce = cole[ni], Ces = coles[ni];
#pragma unroll
      for (int o = 16; o < 64; o <<= 1) {
        Ce += __shfl_xor(Ce, o, 64);
        Ces += __shfl_xor(Ces, o, 64);
      }
      int l = 16 * ni + fr;
      if (fq == 0 && l < Lt) part += (Ces / Ce) * (0.5f / (float)Lt);
    }
    float sim = wave_red_sum(part);
    if (lane == 0) out[(size_t)(2 * by + img) * BT + t] = sim;
  }
}

extern "C" void kernel_launch(void* const* d_in, const int* in_sizes, int n_in,
                              void* d_out, int out_size, void* d_ws, size_t ws_size,
                              hipStream_t stream) {
  // setup_inputs order: img_cls, imgs, cap_cls, caps, img_lens, cap_lens
  const float* imgs = (const float*)d_in[1];
  const float* caps = (const float*)d_in[3];
  const int* img_lens = (const int*)d_in[4];
  const int* cap_lens = (const int*)d_in[5];
  float* out = (float*)d_out;

  _Float16* Ah = (_Float16*)d_ws;                    // [BI*MP][DD] = 12.6 MB
  _Float16* Bh = Ah + (size_t)BI * MP * DD;          // [BT*LCAP][DD] = 16.8 MB

  norm_kernel<<<BI * MP + BT * LCAP, 256, 0, stream>>>(imgs, caps, Ah, Bh);
  sims_kernel<<<2048, 256, 0, stream>>>(Ah, Bh, img_lens, cap_lens, out);
}